// Round 1
// baseline (4740.471 us; speedup 1.0000x reference)
//
#include <hip/hip_runtime.h>
#include <math.h>

#define HD 256
#define G 8
#define BATCH 1024
#define NSTEPS 64
#define DIN 4
#define MMETA 4

#define F(x) ((float)(x))
// dopri5 coefficients: double-precision python values cast to f32 at use (JAX weak typing)
#define A21f F(0.2)
#define A31f F(3.0/40.0)
#define A32f F(9.0/40.0)
#define A41f F(44.0/45.0)
#define A42f F(-56.0/15.0)
#define A43f F(32.0/9.0)
#define A51f F(19372.0/6561.0)
#define A52f F(-25360.0/2187.0)
#define A53f F(64448.0/6561.0)
#define A54f F(-212.0/729.0)
#define A61f F(9017.0/3168.0)
#define A62f F(-355.0/33.0)
#define A63f F(46732.0/5247.0)
#define A64f F(49.0/176.0)
#define A65f F(-5103.0/18656.0)
#define BC0f F(35.0/384.0)
#define BC2f F(500.0/1113.0)
#define BC3f F(125.0/192.0)
#define BC4f F(-2187.0/6784.0)
#define BC5f F(11.0/84.0)
#define EC0f F(35.0/384.0 - 5179.0/57600.0)
#define EC2f F(500.0/1113.0 - 7571.0/16695.0)
#define EC3f F(125.0/192.0 - 393.0/640.0)
#define EC4f F(-2187.0/6784.0 + 92097.0/339200.0)
#define EC5f F(11.0/84.0 - 187.0/2100.0)
#define EC6f F(-1.0/40.0)

#define SELU_SCALE 1.0507009873554805f
#define SELU_ALPHA 1.6732632423543772f

// ---------------- generic transpose: in[R][C] -> out[C][R] ----------------
__global__ void transpose_kernel(const float* __restrict__ in, float* __restrict__ out,
                                 int R, int C) {
    int c = blockIdx.x * 256 + threadIdx.x;
    int r = blockIdx.y;
    if (c < C) out[c * R + r] = in[r * C + c];
}

// ---------------- one MLP layer: zout = act(zin @ W.T + b) ----------------
// Wt is transposed weights: Wt[k*HD + i] = W[i][k]. Thread tid owns output row tid
// for all G elements. zsh is the shared input vector, layout [k][g].
template <bool DO_SELU>
__device__ __forceinline__ void ode_layer(const float* __restrict__ Wt, float bias,
                                          const float (&zin)[G], float (&zout)[G],
                                          float (*zsh)[G], int tid) {
    __syncthreads();                       // previous readers of zsh done
#pragma unroll
    for (int g = 0; g < G; ++g) zsh[tid][g] = zin[g];
    __syncthreads();

    float acc[G];
#pragma unroll
    for (int g = 0; g < G; ++g) acc[g] = bias;

    const float* wcol = Wt + tid;
    float wa[8], wb[8];
#pragma unroll
    for (int u = 0; u < 8; ++u) wa[u] = wcol[u * HD];
#pragma unroll
    for (int u = 0; u < 8; ++u) wb[u] = wcol[(8 + u) * HD];

    for (int k = 0; k < HD; k += 8) {
        float wn[8];
#pragma unroll
        for (int u = 0; u < 8; ++u) wn[u] = wcol[(k + 16 + u) * HD]; // over-read <=16 rows: safe by ws layout
#pragma unroll
        for (int u = 0; u < 8; ++u) {
            float w = wa[u];
            const float4 za = *(const float4*)(&zsh[k + u][0]);
            const float4 zb = *(const float4*)(&zsh[k + u][4]);
            acc[0] = fmaf(w, za.x, acc[0]);
            acc[1] = fmaf(w, za.y, acc[1]);
            acc[2] = fmaf(w, za.z, acc[2]);
            acc[3] = fmaf(w, za.w, acc[3]);
            acc[4] = fmaf(w, zb.x, acc[4]);
            acc[5] = fmaf(w, zb.y, acc[5]);
            acc[6] = fmaf(w, zb.z, acc[6]);
            acc[7] = fmaf(w, zb.w, acc[7]);
        }
#pragma unroll
        for (int u = 0; u < 8; ++u) { wa[u] = wb[u]; wb[u] = wn[u]; }
    }
#pragma unroll
    for (int g = 0; g < G; ++g) {
        float xv = acc[g];
        if (DO_SELU)
            zout[g] = xv > 0.f ? SELU_SCALE * xv : SELU_SCALE * SELU_ALPHA * expm1f(xv);
        else
            zout[g] = xv;
    }
}

struct OdeW {
    const float *W1, *W2, *W3, *W4;
    float b1, b2, b3, b4;
};

__device__ __forceinline__ void ode_f(const OdeW& P, const float (&zin)[G], float (&kout)[G],
                                      float (*zsh)[G], int tid) {
    float h1[G], h2[G];
    ode_layer<true >(P.W1, P.b1, zin, h1, zsh, tid);
    ode_layer<true >(P.W2, P.b2, h1, h2, zsh, tid);
    ode_layer<true >(P.W3, P.b3, h2, h1, zsh, tid);
    ode_layer<false>(P.W4, P.b4, h1, kout, zsh, tid);
}

// ---------------- GRU ----------------
__global__ __launch_bounds__(256) void gru_kernel(
    const float* __restrict__ x, const float* __restrict__ meta,
    const float* __restrict__ WihT, const float* __restrict__ WhhT,
    const float* __restrict__ bih, const float* __restrict__ bhh,
    float* __restrict__ h_out) {
    __shared__ float hsh[HD][G];
    __shared__ float xmsh[8][G];
    const int tid = threadIdx.x;
    const int b0 = blockIdx.x * G;
    const int r0 = tid, r1 = tid + HD, r2 = tid + 2 * HD;
    const float bi0 = bih[r0], bi1 = bih[r1], bi2 = bih[r2];
    const float bh0 = bhh[r0], bh1 = bhh[r1], bh2 = bhh[r2];

    float hreg[G];
#pragma unroll
    for (int g = 0; g < G; ++g) { hsh[tid][g] = 0.f; hreg[g] = 0.f; }

    for (int n = 0; n < NSTEPS; ++n) {
        if (tid < 64) {
            int c = tid & 7, g = tid >> 3;
            xmsh[c][g] = (c < 4) ? x[((b0 + g) * NSTEPS + n) * DIN + c]
                                 : meta[(b0 + g) * MMETA + (c - 4)];
        }
        __syncthreads();   // xm visible; prev-iter hsh writes visible

        float ai0[G], ai1[G], ai2[G], ah0[G], ah1[G], ah2[G];
#pragma unroll
        for (int g = 0; g < G; ++g) {
            ai0[g] = bi0; ai1[g] = bi1; ai2[g] = bi2;
            ah0[g] = bh0; ah1[g] = bh1; ah2[g] = bh2;
        }
        // gi = xm @ Wih.T + bih
#pragma unroll
        for (int c = 0; c < 8; ++c) {
            float w0 = WihT[c * 768 + r0];
            float w1 = WihT[c * 768 + r1];
            float w2 = WihT[c * 768 + r2];
#pragma unroll
            for (int g = 0; g < G; ++g) {
                float xv = xmsh[c][g];
                ai0[g] = fmaf(w0, xv, ai0[g]);
                ai1[g] = fmaf(w1, xv, ai1[g]);
                ai2[g] = fmaf(w2, xv, ai2[g]);
            }
        }
        // gh = h @ Whh.T + bhh
        for (int k = 0; k < HD; k += 4) {
#pragma unroll
            for (int u = 0; u < 4; ++u) {
                float w0 = WhhT[(k + u) * 768 + r0];
                float w1 = WhhT[(k + u) * 768 + r1];
                float w2 = WhhT[(k + u) * 768 + r2];
                const float4 za = *(const float4*)(&hsh[k + u][0]);
                const float4 zb = *(const float4*)(&hsh[k + u][4]);
                ah0[0] = fmaf(w0, za.x, ah0[0]); ah0[1] = fmaf(w0, za.y, ah0[1]);
                ah0[2] = fmaf(w0, za.z, ah0[2]); ah0[3] = fmaf(w0, za.w, ah0[3]);
                ah0[4] = fmaf(w0, zb.x, ah0[4]); ah0[5] = fmaf(w0, zb.y, ah0[5]);
                ah0[6] = fmaf(w0, zb.z, ah0[6]); ah0[7] = fmaf(w0, zb.w, ah0[7]);
                ah1[0] = fmaf(w1, za.x, ah1[0]); ah1[1] = fmaf(w1, za.y, ah1[1]);
                ah1[2] = fmaf(w1, za.z, ah1[2]); ah1[3] = fmaf(w1, za.w, ah1[3]);
                ah1[4] = fmaf(w1, zb.x, ah1[4]); ah1[5] = fmaf(w1, zb.y, ah1[5]);
                ah1[6] = fmaf(w1, zb.z, ah1[6]); ah1[7] = fmaf(w1, zb.w, ah1[7]);
                ah2[0] = fmaf(w2, za.x, ah2[0]); ah2[1] = fmaf(w2, za.y, ah2[1]);
                ah2[2] = fmaf(w2, za.z, ah2[2]); ah2[3] = fmaf(w2, za.w, ah2[3]);
                ah2[4] = fmaf(w2, zb.x, ah2[4]); ah2[5] = fmaf(w2, zb.y, ah2[5]);
                ah2[6] = fmaf(w2, zb.z, ah2[6]); ah2[7] = fmaf(w2, zb.w, ah2[7]);
            }
        }
        float hnew[G];
#pragma unroll
        for (int g = 0; g < G; ++g) {
            float rr = 1.f / (1.f + expf(-(ai0[g] + ah0[g])));
            float zz = 1.f / (1.f + expf(-(ai1[g] + ah1[g])));
            float nn = tanhf(ai2[g] + rr * ah2[g]);
            hnew[g] = (1.f - zz) * nn + zz * hreg[g];
        }
        __syncthreads();   // all reads of hsh/xmsh done
#pragma unroll
        for (int g = 0; g < G; ++g) { hsh[tid][g] = hnew[g]; hreg[g] = hnew[g]; }
    }
#pragma unroll
    for (int g = 0; g < G; ++g) h_out[(b0 + g) * HD + tid] = hreg[g];
}

// ---------------- encoder + reparameterization ----------------
__global__ __launch_bounds__(256) void enc_kernel(
    const float* __restrict__ h_buf, const float* __restrict__ eps,
    const float* __restrict__ W1T, const float* __restrict__ b1,
    const float* __restrict__ W2T, const float* __restrict__ b2,
    float* __restrict__ y0_buf) {
    __shared__ float zsh[HD][G];
    const int tid = threadIdx.x;
    const int b0 = blockIdx.x * G;
#pragma unroll
    for (int g = 0; g < G; ++g) zsh[tid][g] = h_buf[(b0 + g) * HD + tid];
    __syncthreads();
    // layer 1 (relu)
    float acc[G];
    {
        float bb = b1[tid];
#pragma unroll
        for (int g = 0; g < G; ++g) acc[g] = bb;
        for (int k = 0; k < HD; k += 4) {
#pragma unroll
            for (int u = 0; u < 4; ++u) {
                float w = W1T[(k + u) * HD + tid];
                const float4 za = *(const float4*)(&zsh[k + u][0]);
                const float4 zb = *(const float4*)(&zsh[k + u][4]);
                acc[0] = fmaf(w, za.x, acc[0]); acc[1] = fmaf(w, za.y, acc[1]);
                acc[2] = fmaf(w, za.z, acc[2]); acc[3] = fmaf(w, za.w, acc[3]);
                acc[4] = fmaf(w, zb.x, acc[4]); acc[5] = fmaf(w, zb.y, acc[5]);
                acc[6] = fmaf(w, zb.z, acc[6]); acc[7] = fmaf(w, zb.w, acc[7]);
            }
        }
    }
    __syncthreads();
#pragma unroll
    for (int g = 0; g < G; ++g) zsh[tid][g] = fmaxf(acc[g], 0.f);
    __syncthreads();
    // layer 2: rows tid (mean) and tid+256 (std)
    float am[G], as[G];
    {
        float bm = b2[tid], bs = b2[tid + HD];
#pragma unroll
        for (int g = 0; g < G; ++g) { am[g] = bm; as[g] = bs; }
        for (int k = 0; k < HD; k += 4) {
#pragma unroll
            for (int u = 0; u < 4; ++u) {
                float wm = W2T[(k + u) * 512 + tid];
                float ws2 = W2T[(k + u) * 512 + HD + tid];
                const float4 za = *(const float4*)(&zsh[k + u][0]);
                const float4 zb = *(const float4*)(&zsh[k + u][4]);
                am[0] = fmaf(wm, za.x, am[0]); am[1] = fmaf(wm, za.y, am[1]);
                am[2] = fmaf(wm, za.z, am[2]); am[3] = fmaf(wm, za.w, am[3]);
                am[4] = fmaf(wm, zb.x, am[4]); am[5] = fmaf(wm, zb.y, am[5]);
                am[6] = fmaf(wm, zb.z, am[6]); am[7] = fmaf(wm, zb.w, am[7]);
                as[0] = fmaf(ws2, za.x, as[0]); as[1] = fmaf(ws2, za.y, as[1]);
                as[2] = fmaf(ws2, za.z, as[2]); as[3] = fmaf(ws2, za.w, as[3]);
                as[4] = fmaf(ws2, zb.x, as[4]); as[5] = fmaf(ws2, zb.y, as[5]);
                as[6] = fmaf(ws2, zb.z, as[6]); as[7] = fmaf(ws2, zb.w, as[7]);
            }
        }
    }
#pragma unroll
    for (int g = 0; g < G; ++g)
        y0_buf[(b0 + g) * HD + tid] = eps[(b0 + g) * HD + tid] * as[g] + am[g];
}

// ---------------- dopri5 over 4 intervals + final FC ----------------
__global__ __launch_bounds__(256) void ode_kernel(
    const float* __restrict__ y0_buf, const float* __restrict__ times,
    const float* __restrict__ doses, const float* __restrict__ WT,
    const float* __restrict__ ob1, const float* __restrict__ ob2,
    const float* __restrict__ ob3, const float* __restrict__ ob4,
    const float* __restrict__ meta, const float* __restrict__ fcW,
    const float* __restrict__ fcb, float* __restrict__ out) {
    __shared__ float zsh[HD][G];
    __shared__ float red[4][G];
    const int tid = threadIdx.x;
    const int b0 = blockIdx.x * G;

    OdeW P;
    P.W1 = WT; P.W2 = WT + 65536; P.W3 = WT + 131072; P.W4 = WT + 196608;
    P.b1 = ob1[tid]; P.b2 = ob2[tid]; P.b3 = ob3[tid]; P.b4 = ob4[tid];

    float y[G];
#pragma unroll
    for (int g = 0; g < G; ++g) y[g] = y0_buf[(b0 + g) * HD + tid];

    for (int j = 0; j < 4; ++j) {
        float t[G], dt[G], t1v[G], ysv[G];
        bool act0[G];
#pragma unroll
        for (int g = 0; g < G; ++g) {
            float tt0 = times[((j * BATCH) + (b0 + g)) * 2 + 0];
            float tt1 = times[((j * BATCH) + (b0 + g)) * 2 + 1];
            float ds = doses[j * BATCH + (b0 + g)];
            act0[g] = tt0 < tt1;
            ysv[g] = y[g];
            y[g] += ds;
            t[g] = tt0; t1v[g] = tt1;
            dt[g] = fmaxf(tt1 - tt0, 1e-6f) * 0.1f;
        }
        float k1[G], k2[G], k3[G], k4[G], k5[G], k6[G], k7[G], y5[G], z[G];
        ode_f(P, y, k1, zsh, tid);   // FSAL seed

        for (int step = 0; step < 32; ++step) {
            bool act[G]; float d[G];
            bool anyact = false;
#pragma unroll
            for (int g = 0; g < G; ++g) {
                act[g] = t[g] < t1v[g];
                anyact = anyact || act[g];
                // NaN-propagating clip (matches jnp semantics)
                float dtc = dt[g];
                if (dtc < 0.f) dtc = 0.f;
                float rem = t1v[g] - t[g];
                if (rem < 0.f) rem = 0.f;
                if (dtc > rem) dtc = rem;
                d[g] = dtc;
            }
            if (!anyact) break;   // uniform: remaining reference iterations are no-ops

#pragma unroll
            for (int g = 0; g < G; ++g) z[g] = y[g] + d[g] * (A21f * k1[g]);
            ode_f(P, z, k2, zsh, tid);
#pragma unroll
            for (int g = 0; g < G; ++g) z[g] = y[g] + d[g] * (A31f * k1[g] + A32f * k2[g]);
            ode_f(P, z, k3, zsh, tid);
#pragma unroll
            for (int g = 0; g < G; ++g) z[g] = y[g] + d[g] * (A41f * k1[g] + A42f * k2[g] + A43f * k3[g]);
            ode_f(P, z, k4, zsh, tid);
#pragma unroll
            for (int g = 0; g < G; ++g) z[g] = y[g] + d[g] * (A51f * k1[g] + A52f * k2[g] + A53f * k3[g] + A54f * k4[g]);
            ode_f(P, z, k5, zsh, tid);
#pragma unroll
            for (int g = 0; g < G; ++g) z[g] = y[g] + d[g] * (A61f * k1[g] + A62f * k2[g] + A63f * k3[g] + A64f * k4[g] + A65f * k5[g]);
            ode_f(P, z, k6, zsh, tid);
#pragma unroll
            for (int g = 0; g < G; ++g) y5[g] = y[g] + d[g] * (BC0f * k1[g] + BC2f * k3[g] + BC3f * k4[g] + BC4f * k5[g] + BC5f * k6[g]);
            ode_f(P, y5, k7, zsh, tid);

            float s[G];
#pragma unroll
            for (int g = 0; g < G; ++g) {
                float err = d[g] * (EC0f * k1[g] + EC2f * k3[g] + EC3f * k4[g] + EC4f * k5[g] + EC5f * k6[g] + EC6f * k7[g]);
                float sc = 1e-6f + 1e-3f * fmaxf(fabsf(y[g]), fabsf(y5[g]));
                float r = err / sc;
                s[g] = r * r;
            }
            // block reduction over the 256 components
#pragma unroll
            for (int off = 32; off; off >>= 1)
#pragma unroll
                for (int g = 0; g < G; ++g) s[g] += __shfl_xor(s[g], off, 64);
            __syncthreads();
            if ((tid & 63) == 0) {
#pragma unroll
                for (int g = 0; g < G; ++g) red[tid >> 6][g] = s[g];
            }
            __syncthreads();
#pragma unroll
            for (int g = 0; g < G; ++g) s[g] = (red[0][g] + red[1][g]) + (red[2][g] + red[3][g]);

#pragma unroll
            for (int g = 0; g < G; ++g) {
                float en = sqrtf(s[g] * (1.0f / HD));
                bool accg = (en <= 1.0f) && act[g];
                y[g] = accg ? y5[g] : y[g];
                t[g] = accg ? t[g] + d[g] : t[g];
                k1[g] = accg ? k7[g] : k1[g];   // FSAL
                float fac = 0.9f * powf(en + 1e-10f, -0.2f);
                if (fac < 0.2f) fac = 0.2f;     // NaN-propagating clip
                if (fac > 10.f) fac = 10.f;
                dt[g] = act[g] ? fmaxf(d[g], 1e-8f) * fac : dt[g];
            }
        }
#pragma unroll
        for (int g = 0; g < G; ++g) y[g] = act0[g] ? y[g] : ysv[g];
    }

    // final FC: out[b] = y . fcW[0:256] + meta . fcW[256:260] + fcb
    float part[G];
    float fw = fcW[tid];
#pragma unroll
    for (int g = 0; g < G; ++g) part[g] = y[g] * fw;
#pragma unroll
    for (int off = 32; off; off >>= 1)
#pragma unroll
        for (int g = 0; g < G; ++g) part[g] += __shfl_xor(part[g], off, 64);
    __syncthreads();
    if ((tid & 63) == 0) {
#pragma unroll
        for (int g = 0; g < G; ++g) red[tid >> 6][g] = part[g];
    }
    __syncthreads();
#pragma unroll
    for (int g = 0; g < G; ++g) {
        if (tid == g) {
            float v = (red[0][g] + red[1][g]) + (red[2][g] + red[3][g]);
#pragma unroll
            for (int m = 0; m < MMETA; ++m) v += meta[(b0 + g) * MMETA + m] * fcW[HD + m];
            out[b0 + g] = v + fcb[0];
        }
    }
}

extern "C" void kernel_launch(void* const* d_in, const int* in_sizes, int n_in,
                              void* d_out, int out_size, void* d_ws, size_t ws_size,
                              hipStream_t stream) {
    const float* x     = (const float*)d_in[0];
    const float* meta  = (const float*)d_in[1];
    const float* eps   = (const float*)d_in[2];
    const float* times = (const float*)d_in[3];
    const float* doses = (const float*)d_in[4];
    const float* Wih   = (const float*)d_in[5];
    const float* Whh   = (const float*)d_in[6];
    const float* bih   = (const float*)d_in[7];
    const float* bhh   = (const float*)d_in[8];
    const float* eW1   = (const float*)d_in[9];
    const float* eb1   = (const float*)d_in[10];
    const float* eW2   = (const float*)d_in[11];
    const float* eb2   = (const float*)d_in[12];
    const float* oW1   = (const float*)d_in[13];
    const float* ob1   = (const float*)d_in[14];
    const float* oW2   = (const float*)d_in[15];
    const float* ob2   = (const float*)d_in[16];
    const float* oW3   = (const float*)d_in[17];
    const float* ob3   = (const float*)d_in[18];
    const float* oW4   = (const float*)d_in[19];
    const float* ob4   = (const float*)d_in[20];
    const float* fcW   = (const float*)d_in[21];
    const float* fcb   = (const float*)d_in[22];

    float* ws   = (float*)d_ws;
    float* WihT = ws;             // [8][768]      6144
    float* WhhT = WihT + 6144;    // [256][768]    196608
    float* eW1T = WhhT + 196608;  // [256][256]    65536
    float* eW2T = eW1T + 65536;   // [256][512]    131072
    float* oWT  = eW2T + 131072;  // [4][256][256] 262144
    float* hbuf = oWT + 262144;   // [1024][256]   262144
    float* y0b  = hbuf + 262144;  // [1024][256]   262144

    transpose_kernel<<<dim3(1, 768), 256, 0, stream>>>(Wih, WihT, 768, 8);
    transpose_kernel<<<dim3(1, 768), 256, 0, stream>>>(Whh, WhhT, 768, 256);
    transpose_kernel<<<dim3(1, 256), 256, 0, stream>>>(eW1, eW1T, 256, 256);
    transpose_kernel<<<dim3(1, 512), 256, 0, stream>>>(eW2, eW2T, 512, 256);
    transpose_kernel<<<dim3(1, 256), 256, 0, stream>>>(oW1, oWT, 256, 256);
    transpose_kernel<<<dim3(1, 256), 256, 0, stream>>>(oW2, oWT + 65536, 256, 256);
    transpose_kernel<<<dim3(1, 256), 256, 0, stream>>>(oW3, oWT + 131072, 256, 256);
    transpose_kernel<<<dim3(1, 256), 256, 0, stream>>>(oW4, oWT + 196608, 256, 256);

    gru_kernel<<<BATCH / G, 256, 0, stream>>>(x, meta, WihT, WhhT, bih, bhh, hbuf);
    enc_kernel<<<BATCH / G, 256, 0, stream>>>(hbuf, eps, eW1T, eb1, eW2T, eb2, y0b);
    ode_kernel<<<BATCH / G, 256, 0, stream>>>(y0b, times, doses, oWT, ob1, ob2, ob3, ob4,
                                              meta, fcW, fcb, (float*)d_out);
}